// Round 1
// baseline (2136.223 us; speedup 1.0000x reference)
//
#include <hip/hip_runtime.h>
#include <hip/hip_bf16.h>

// Dims
#define BB 32
#define TT 64
#define HH 512
#define EE 512
#define VV 32000

typedef float f32x4 __attribute__((ext_vector_type(4)));
typedef __bf16 bf16x8 __attribute__((ext_vector_type(8)));
typedef unsigned short u16x8 __attribute__((ext_vector_type(8)));

static __device__ __forceinline__ unsigned short f2bf(float f) {
  unsigned int u = __builtin_bit_cast(unsigned int, f);
  u += 0x7fffu + ((u >> 16) & 1u);   // RNE; inputs are finite
  return (unsigned short)(u >> 16);
}

// ---- fp32 -> bf16 bulk convert (8 elems/thread) ----
__global__ __launch_bounds__(256) void k_cvt_bf16(const float* __restrict__ in,
                                                  unsigned short* __restrict__ out,
                                                  int n8) {
  int tid = blockIdx.x * 256 + threadIdx.x;
  if (tid >= n8) return;
  int idx = tid * 8;
  float4 a = *(const float4*)(in + idx);
  float4 b = *(const float4*)(in + idx + 4);
  u16x8 o;
  o[0] = f2bf(a.x); o[1] = f2bf(a.y); o[2] = f2bf(a.z); o[3] = f2bf(a.w);
  o[4] = f2bf(b.x); o[5] = f2bf(b.y); o[6] = f2bf(b.z); o[7] = f2bf(b.w);
  *(u16x8*)(out + idx) = o;
}

// ---- embedding gather -> bf16, layout [t*B+b][E] ----
__global__ __launch_bounds__(256) void k_emb(const int* __restrict__ seq,
                                             const float* __restrict__ emb,
                                             unsigned short* __restrict__ out) {
  int tid = blockIdx.x * 256 + threadIdx.x;   // 2048*512/8 = 131072 threads
  int idx = tid * 8;
  int m = idx >> 9;          // t*32 + b
  int e0 = idx & 511;
  int t = m >> 5, b = m & 31;
  int s = seq[b * TT + t];
  const float* src = emb + (size_t)s * EE + e0;
  float4 a = *(const float4*)(src);
  float4 c = *(const float4*)(src + 4);
  u16x8 o;
  o[0] = f2bf(a.x); o[1] = f2bf(a.y); o[2] = f2bf(a.z); o[3] = f2bf(a.w);
  o[4] = f2bf(c.x); o[5] = f2bf(c.y); o[6] = f2bf(c.z); o[7] = f2bf(c.w);
  *(u16x8*)(out + m * EE + e0) = o;
}

// ---- W_eff = W_out[:, :H] @ W_in + W_out[:, H:]  (fp32, one-time) ----
__global__ __launch_bounds__(256) void k_weff(const float* __restrict__ W_out,
                                              const float* __restrict__ W_in,
                                              float* __restrict__ W_eff) {
  __shared__ float sa[16][17], sb[16][17];
  const int t16 = threadIdx.x & 15, ty = threadIdx.x >> 4;
  const int i = blockIdx.y * 16 + ty, m = blockIdx.x * 16 + t16;
  float acc = 0.f;
  for (int k0 = 0; k0 < HH; k0 += 16) {
    sa[ty][t16] = W_out[i * 1024 + k0 + t16];
    sb[ty][t16] = W_in[(k0 + ty) * HH + m];
    __syncthreads();
#pragma unroll
    for (int kk = 0; kk < 16; ++kk) acc += sa[ty][kk] * sb[kk][t16];
    __syncthreads();
  }
  W_eff[i * HH + m] = acc + W_out[i * 1024 + HH + m];
}

__global__ __launch_bounds__(256) void k_beff(const float* __restrict__ W_out,
                                              const float* __restrict__ b_in,
                                              const float* __restrict__ b_out,
                                              float* __restrict__ b_eff) {
  int i = blockIdx.x * 256 + threadIdx.x;
  if (i >= HH) return;
  float acc = b_out[i];
  for (int k = 0; k < HH; ++k) acc += W_out[i * 1024 + k] * b_in[k];
  b_eff[i] = acc;
}

// ---- bf16 MFMA GEMM: C[M][N] = A[M][K] * Bm[N][K]^T (+bias1+bias2) ----
// 128x128 tile, 4 waves, BK=32, padded LDS (row stride 40 elems = 80B, 16B-aligned)
__global__ __launch_bounds__(256) void k_gemm(const unsigned short* __restrict__ A, int lda,
                                              const unsigned short* __restrict__ Bm, int ldb,
                                              float* __restrict__ C, int ldc,
                                              const float* __restrict__ bias1,
                                              const float* __restrict__ bias2,
                                              int K) {
  __shared__ unsigned short As[128][40];
  __shared__ unsigned short Bs[128][40];
  const int tx = threadIdx.x;
  const int lane = tx & 63, w = tx >> 6;
  const int wrow = (w >> 1) * 64, wcol = (w & 1) * 64;
  const int l15 = lane & 15, lk = lane >> 4;
  const int m0 = blockIdx.y * 128, n0 = blockIdx.x * 128;
  f32x4 acc[4][4] = {};
  for (int k0 = 0; k0 < K; k0 += 32) {
#pragma unroll
    for (int u = 0; u < 2; ++u) {
      int c = u * 256 + tx;               // 512 16B-chunks per matrix
      int row = c >> 2, cc = (c & 3) * 8;
      *(int4*)(&As[row][cc]) = *(const int4*)(A + (size_t)(m0 + row) * lda + k0 + cc);
      *(int4*)(&Bs[row][cc]) = *(const int4*)(Bm + (size_t)(n0 + row) * ldb + k0 + cc);
    }
    __syncthreads();
    bf16x8 av[4], bv[4];
#pragma unroll
    for (int mi = 0; mi < 4; ++mi)
      av[mi] = __builtin_bit_cast(bf16x8, *(const int4*)(&As[wrow + mi * 16 + l15][lk * 8]));
#pragma unroll
    for (int ni = 0; ni < 4; ++ni)
      bv[ni] = __builtin_bit_cast(bf16x8, *(const int4*)(&Bs[wcol + ni * 16 + l15][lk * 8]));
#pragma unroll
    for (int mi = 0; mi < 4; ++mi)
#pragma unroll
      for (int ni = 0; ni < 4; ++ni)
        acc[mi][ni] = __builtin_amdgcn_mfma_f32_16x16x32_bf16(av[mi], bv[ni], acc[mi][ni], 0, 0, 0);
    __syncthreads();
  }
#pragma unroll
  for (int mi = 0; mi < 4; ++mi) {
#pragma unroll
    for (int ni = 0; ni < 4; ++ni) {
      int row = m0 + wrow + mi * 16 + lk * 4;
      int col = n0 + wcol + ni * 16 + l15;
      float bb = 0.f;
      if (bias1) bb += bias1[col];
      if (bias2) bb += bias2[col];
#pragma unroll
      for (int q = 0; q < 4; ++q)
        C[(size_t)(row + q) * ldc + col] = acc[mi][ni][q] + bb;
    }
  }
}

// ---- per-step: gates + cell update (fp32) ----
// block = 256 thr: b=tx&31, r=tx>>5 -> (il=r>>2, gate=r&3); 2 i-values/block, grid=256
__global__ __launch_bounds__(256) void k_gates(const float* __restrict__ xproj_t,
                                               const float* __restrict__ feed,
                                               const float* __restrict__ h_in,
                                               float* __restrict__ c,
                                               float* __restrict__ h_out,
                                               const float* __restrict__ W_ih,
                                               const float* __restrict__ W_hh) {
  __shared__ float s_f[32][132];
  __shared__ float s_h[32][132];
  __shared__ float s_g[8][33];
  const int tx = threadIdx.x;
  const int b = tx & 31, r = tx >> 5;
  const int il = r >> 2, gate = r & 3;
  const int i0 = blockIdx.x * 2;
  const int j = gate * 512 + i0 + il;
  float acc = xproj_t[b * 2048 + j];
  const float* wf = W_ih + (size_t)j * 1024 + 512;   // feed half of W_ih
  const float* wh = W_hh + (size_t)j * 512;
  for (int k0 = 0; k0 < 512; k0 += 128) {
#pragma unroll
    for (int u = 0; u < 4; ++u) {
      int idx = u * 256 + tx;
      int rr = idx >> 5, cc = (idx & 31) * 4;
      *(float4*)(&s_f[rr][cc]) = *(const float4*)(feed + rr * 512 + k0 + cc);
      *(float4*)(&s_h[rr][cc]) = *(const float4*)(h_in + rr * 512 + k0 + cc);
    }
    __syncthreads();
#pragma unroll 8
    for (int k = 0; k < 128; k += 4) {
      float4 fv = *(const float4*)(&s_f[b][k]);
      float4 hv = *(const float4*)(&s_h[b][k]);
      float4 wfv = *(const float4*)(wf + k0 + k);
      float4 whv = *(const float4*)(wh + k0 + k);
      acc += fv.x * wfv.x + fv.y * wfv.y + fv.z * wfv.z + fv.w * wfv.w;
      acc += hv.x * whv.x + hv.y * whv.y + hv.z * whv.z + hv.w * whv.w;
    }
    __syncthreads();
  }
  s_g[r][b] = acc;
  __syncthreads();
  if (tx < 64) {
    int b2 = tx & 31, il2 = tx >> 5;
    int ii = i0 + il2;
    float gi = s_g[il2 * 4 + 0][b2];
    float gf = s_g[il2 * 4 + 1][b2];
    float gg = s_g[il2 * 4 + 2][b2];
    float go = s_g[il2 * 4 + 3][b2];
    float cold = c[b2 * 512 + ii];
    float si = 1.f / (1.f + __expf(-gi));
    float sf = 1.f / (1.f + __expf(-gf));
    float so = 1.f / (1.f + __expf(-go));
    float cn = sf * cold + si * tanhf(gg);
    c[b2 * 512 + ii] = cn;
    h_out[b2 * 512 + ii] = so * tanhf(cn);
  }
}

// ---- per-step: feed/out = tanh(h @ W_eff^T + b_eff) ----
__global__ __launch_bounds__(64) void k_out(const float* __restrict__ h,
                                            const float* __restrict__ W_eff,
                                            const float* __restrict__ b_eff,
                                            float* __restrict__ out) {
  const int tx = threadIdx.x;
  const int b = tx & 31, il = tx >> 5;
  const int i = blockIdx.x * 2 + il;
  const float* hb = h + b * 512;
  const float* wi = W_eff + (size_t)i * 512;
  float acc = 0.f;
#pragma unroll 8
  for (int k = 0; k < 512; k += 4) {
    float4 hv = *(const float4*)(hb + k);
    float4 wv = *(const float4*)(wi + k);
    acc += hv.x * wv.x + hv.y * wv.y + hv.z * wv.z + hv.w * wv.w;
  }
  out[b * 512 + i] = tanhf(acc + b_eff[i]);
}

// ---- outs [T][B][H] fp32 -> A_bt [(b*T+t)][H] bf16 ----
__global__ __launch_bounds__(256) void k_tr(const float* __restrict__ outs,
                                            unsigned short* __restrict__ abt) {
  int tid = blockIdx.x * 256 + threadIdx.x;   // 131072 threads
  int idx = tid * 8;
  int m = idx >> 9;        // b*64 + t
  int h0 = idx & 511;
  int b = m >> 6, t = m & 63;
  const float* src = outs + (size_t)(t * 32 + b) * 512 + h0;
  float4 a = *(const float4*)(src);
  float4 c = *(const float4*)(src + 4);
  u16x8 o;
  o[0] = f2bf(a.x); o[1] = f2bf(a.y); o[2] = f2bf(a.z); o[3] = f2bf(a.w);
  o[4] = f2bf(c.x); o[5] = f2bf(c.y); o[6] = f2bf(c.z); o[7] = f2bf(c.w);
  *(u16x8*)(abt + m * 512 + h0) = o;
}

extern "C" void kernel_launch(void* const* d_in, const int* in_sizes, int n_in,
                              void* d_out, int out_size, void* d_ws, size_t ws_size,
                              hipStream_t stream) {
  const int*   seq      = (const int*)d_in[0];
  // d_in[1] = encoder_outputs: attention scores are dead code -> unused
  const float* enc_h    = (const float*)d_in[2];
  const float* enc_c    = (const float*)d_in[3];
  const float* emb      = (const float*)d_in[4];
  const float* W_ih     = (const float*)d_in[5];
  const float* b_ih     = (const float*)d_in[6];
  const float* W_hh     = (const float*)d_in[7];
  const float* b_hh     = (const float*)d_in[8];
  const float* W_inp    = (const float*)d_in[9];
  const float* b_inp    = (const float*)d_in[10];
  const float* W_outp   = (const float*)d_in[11];
  const float* b_outp   = (const float*)d_in[12];
  const float* W_final  = (const float*)d_in[13];
  const float* b_final  = (const float*)d_in[14];
  float* logits = (float*)d_out;

  char* ws = (char*)d_ws;
  size_t off = 0;
  auto alloc = [&](size_t bytes) {
    char* p = ws + off;
    off += (bytes + 255) & ~(size_t)255;
    return p;
  };
  unsigned short* wih_b  = (unsigned short*)alloc((size_t)2048 * 1024 * 2);
  unsigned short* wfin_b = (unsigned short*)alloc((size_t)VV * HH * 2);
  unsigned short* emb_b  = (unsigned short*)alloc((size_t)2048 * 512 * 2);
  float* xproj = (float*)alloc((size_t)2048 * 2048 * 4);
  float* W_eff = (float*)alloc((size_t)512 * 512 * 4);
  float* b_eff = (float*)alloc((size_t)512 * 4);
  float* hbuf0 = (float*)alloc((size_t)32 * 512 * 4);
  float* hbuf1 = (float*)alloc((size_t)32 * 512 * 4);
  float* cbuf  = (float*)alloc((size_t)32 * 512 * 4);
  float* feed0 = (float*)alloc((size_t)32 * 512 * 4);
  float* outs  = (float*)alloc((size_t)64 * 32 * 512 * 4);
  unsigned short* abt = (unsigned short*)alloc((size_t)2048 * 512 * 2);

  // one-time per call: conversions + effective recurrence weights
  hipLaunchKernelGGL(k_cvt_bf16, dim3(1024), dim3(256), 0, stream, W_ih, wih_b, 2048 * 1024 / 8);
  hipLaunchKernelGGL(k_cvt_bf16, dim3(8000), dim3(256), 0, stream, W_final, wfin_b, VV * HH / 8);
  hipLaunchKernelGGL(k_emb, dim3(512), dim3(256), 0, stream, seq, emb, emb_b);
  hipLaunchKernelGGL(k_weff, dim3(32, 32), dim3(256), 0, stream, W_outp, W_inp, W_eff);
  hipLaunchKernelGGL(k_beff, dim3(2), dim3(256), 0, stream, W_outp, b_inp, b_outp, b_eff);
  hipMemcpyAsync(hbuf0, enc_h, (size_t)32 * 512 * 4, hipMemcpyDeviceToDevice, stream);
  hipMemcpyAsync(cbuf, enc_c, (size_t)32 * 512 * 4, hipMemcpyDeviceToDevice, stream);
  hipMemsetAsync(feed0, 0, (size_t)32 * 512 * 4, stream);

  // xproj[t*B+b][4H] = emb_bf16 @ W_ih[:, :E]^T + b_ih + b_hh
  hipLaunchKernelGGL(k_gemm, dim3(16, 16), dim3(256), 0, stream,
                     emb_b, 512, wih_b, 1024, xproj, 2048, b_ih, b_hh, 512);

  float* hb[2] = {hbuf0, hbuf1};
  for (int t = 0; t < TT; ++t) {
    const float* feed = (t == 0) ? feed0 : (outs + (size_t)(t - 1) * 32 * 512);
    float* hcur = hb[t & 1];
    float* hnext = hb[(t & 1) ^ 1];
    hipLaunchKernelGGL(k_gates, dim3(256), dim3(256), 0, stream,
                       xproj + (size_t)t * 32 * 2048, feed, hcur, cbuf, hnext, W_ih, W_hh);
    hipLaunchKernelGGL(k_out, dim3(256), dim3(64), 0, stream,
                       hnext, W_eff, b_eff, outs + (size_t)t * 32 * 512);
  }

  hipLaunchKernelGGL(k_tr, dim3(512), dim3(256), 0, stream, outs, abt);
  // logits[b*T+t][V] = A_bt @ W_final^T + b_final
  hipLaunchKernelGGL(k_gemm, dim3(250, 16), dim3(256), 0, stream,
                     abt, 512, wfin_b, 512, logits, 32000, b_final, (const float*)nullptr, 512);
}